// Round 4
// baseline (610.827 us; speedup 1.0000x reference)
//
#include <hip/hip_runtime.h>
#include <hip/hip_bf16.h>
#include <math.h>

// Inputs fp32 (confirmed R3: NaN vanished when casts changed bf16->fp32).
// Output fp32 (harness rule: reference output dtype; R3's bf16 write gave the
// predicted uncorrelated-read signature absmax 3.36). GEMM math: bf16 MFMA,
// fp32 accumulate; harness compares in bf16-tolerant space (2% threshold).
typedef __attribute__((ext_vector_type(8))) short  short8;   // 8 bf16 (16 B)
typedef __attribute__((ext_vector_type(4))) float  floatx4;  // MFMA C/D frag

__device__ __forceinline__ ushort f2bf(float f) {
    __hip_bfloat16 hb = __float2bfloat16(f);  // round-to-nearest-even
    return *(ushort*)&hb;
}
__device__ __forceinline__ short8 pack8(float4 a, float4 b) {
    union { short8 v; ushort u[8]; } r;
    r.u[0] = f2bf(a.x); r.u[1] = f2bf(a.y); r.u[2] = f2bf(a.z); r.u[3] = f2bf(a.w);
    r.u[4] = f2bf(b.x); r.u[5] = f2bf(b.y); r.u[6] = f2bf(b.z); r.u[7] = f2bf(b.w);
    return r.v;
}

// ---------------------------------------------------------------------------
// fp32 -> bf16 bulk convert. n8 = elements/8 (exact multiples here).
__global__ __launch_bounds__(256) void k_cvt(const float* __restrict__ in,
                                             ushort* __restrict__ out, int n8) {
    int i = blockIdx.x * 256 + threadIdx.x;
    if (i >= n8) return;
    const float4* p = reinterpret_cast<const float4*>(in) + (size_t)i * 2;
    float4 a = p[0], b = p[1];
    *reinterpret_cast<short8*>(out + (size_t)i * 8) = pack8(a, b);
}

// ---------------------------------------------------------------------------
// fc1_w fp32 [4096 d][1024 s] -> fc1T bf16 [1024 s][4096 d]. 64x64 tiles.
__global__ __launch_bounds__(256) void k_transpose(const float* __restrict__ in,
                                                   ushort* __restrict__ out) {
    __shared__ float sm[64][65];
    const int tid = threadIdx.x;
    const int s0 = blockIdx.x * 64;   // input col tile (s)
    const int d0 = blockIdx.y * 64;   // input row tile (d)
#pragma unroll
    for (int i = 0; i < 4; ++i) {
        int lin = i * 256 + tid;
        int dr  = lin >> 4;          // 0..63
        int sc4 = lin & 15;          // 0..15 (float4 of s)
        float4 v = *reinterpret_cast<const float4*>(&in[(size_t)(d0 + dr) * 1024 + s0 + sc4 * 4]);
        sm[dr][sc4 * 4 + 0] = v.x; sm[dr][sc4 * 4 + 1] = v.y;
        sm[dr][sc4 * 4 + 2] = v.z; sm[dr][sc4 * 4 + 3] = v.w;
    }
    __syncthreads();
#pragma unroll
    for (int i = 0; i < 8; ++i) {
        int lin = i * 256 + tid;
        int dc2 = lin & 31;          // pairs of d (coalesced store dim)
        int sr  = lin >> 5;          // 0..63
        uint lo = (uint)f2bf(sm[dc2 * 2][sr]);
        uint hi = (uint)f2bf(sm[dc2 * 2 + 1][sr]);
        *reinterpret_cast<uint*>(&out[(size_t)(s0 + sr) * 4096 + d0 + dc2 * 2]) = lo | (hi << 16);
    }
}

// ---------------------------------------------------------------------------
// C[m][n] = sum_k A[m][k] * B^T[n][k].  128x128 tile, BK=32, 4 waves (2x2).
// AFP32: A is fp32, converted to bf16 during staging. B always bf16.
// EPI=0: attn epilogue ((acc + bias[t]) * mask[s][t]) -> attnT[t][s] bf16 (ws)
// EPI=1: exact-erf GELU -> C[m][n] fp32 (d_out)
template <int AFP32, int EPI>
__global__ __launch_bounds__(256) void k_gemm(const void* __restrict__ Ap,
                                              const ushort* __restrict__ B,
                                              const float* __restrict__ bias,
                                              const float* __restrict__ mask,
                                              void* __restrict__ Cout,
                                              int lda, int ldb, int ksteps) {
    __shared__ ushort As[128 * 32];
    __shared__ ushort Bs[128 * 32];
    const int tid  = threadIdx.x;
    const int wave = tid >> 6, lane = tid & 63;
    const int wm = wave >> 1, wn = wave & 1;
    const int quad = lane >> 4, m16 = lane & 15;
    const int n0 = blockIdx.x * 128;
    const int m0 = blockIdx.y * 128;

    floatx4 acc[4][4];
    const floatx4 zero = {0.f, 0.f, 0.f, 0.f};
#pragma unroll
    for (int i = 0; i < 4; ++i)
#pragma unroll
        for (int j = 0; j < 4; ++j) acc[i][j] = zero;

    const int s_r = tid >> 2;  // staging row 0..63 (+64 on second half)
    const int s_c = tid & 3;   // staging k-chunk of 8

    for (int kt = 0; kt < ksteps; ++kt) {
        const int k0 = kt * 32;
        short8 a0, a1, b0, b1;
        if (AFP32) {
            const float* Af = (const float*)Ap;
            const float* r0 = &Af[(size_t)(m0 + s_r) * lda + k0 + s_c * 8];
            const float* r1 = &Af[(size_t)(m0 + 64 + s_r) * lda + k0 + s_c * 8];
            a0 = pack8(*reinterpret_cast<const float4*>(r0), *reinterpret_cast<const float4*>(r0 + 4));
            a1 = pack8(*reinterpret_cast<const float4*>(r1), *reinterpret_cast<const float4*>(r1 + 4));
        } else {
            const ushort* Ab = (const ushort*)Ap;
            a0 = *reinterpret_cast<const short8*>(&Ab[(size_t)(m0 + s_r) * lda + k0 + s_c * 8]);
            a1 = *reinterpret_cast<const short8*>(&Ab[(size_t)(m0 + 64 + s_r) * lda + k0 + s_c * 8]);
        }
        b0 = *reinterpret_cast<const short8*>(&B[(size_t)(n0 + s_r) * ldb + k0 + s_c * 8]);
        b1 = *reinterpret_cast<const short8*>(&B[(size_t)(n0 + 64 + s_r) * ldb + k0 + s_c * 8]);
        __syncthreads();  // prior iter's LDS reads complete before overwrite
        *reinterpret_cast<short8*>(&As[(s_r)      * 32 + s_c * 8]) = a0;
        *reinterpret_cast<short8*>(&As[(64 + s_r) * 32 + s_c * 8]) = a1;
        *reinterpret_cast<short8*>(&Bs[(s_r)      * 32 + s_c * 8]) = b0;
        *reinterpret_cast<short8*>(&Bs[(64 + s_r) * 32 + s_c * 8]) = b1;
        __syncthreads();  // staging visible

        short8 aF[4], bF[4];
#pragma unroll
        for (int i = 0; i < 4; ++i)
            aF[i] = *reinterpret_cast<const short8*>(&As[(wm * 64 + i * 16 + m16) * 32 + quad * 8]);
#pragma unroll
        for (int j = 0; j < 4; ++j)
            bF[j] = *reinterpret_cast<const short8*>(&Bs[(wn * 64 + j * 16 + m16) * 32 + quad * 8]);
#pragma unroll
        for (int i = 0; i < 4; ++i)
#pragma unroll
            for (int j = 0; j < 4; ++j)
                acc[i][j] = __builtin_amdgcn_mfma_f32_16x16x32_bf16(aF[i], bF[j], acc[i][j], 0, 0, 0);
    }

    // C/D layout (verified m89/m91): col = lane&15, row = quad*4 + reg
#pragma unroll
    for (int i = 0; i < 4; ++i) {
#pragma unroll
        for (int j = 0; j < 4; ++j) {
            const int col = n0 + wn * 64 + j * 16 + m16;
            float bv = 0.f;
            if (EPI == 0) bv = bias[col];
#pragma unroll
            for (int rr = 0; rr < 4; ++rr) {
                const int row = m0 + wm * 64 + i * 16 + quad * 4 + rr;
                float v = acc[i][j][rr];
                if (EPI == 0) {
                    v = (v + bv) * mask[(size_t)row * 1024 + col];
                    ((ushort*)Cout)[(size_t)col * 1024 + row] = f2bf(v);  // attnT[t][s]
                } else {
                    float g = 0.5f * v * (1.0f + erff(v * 0.70710678118654752f));
                    ((float*)Cout)[(size_t)row * 1024 + col] = g;  // fp32 out
                }
            }
        }
    }
}

// ---------------------------------------------------------------------------
extern "C" void kernel_launch(void* const* d_in, const int* in_sizes, int n_in,
                              void* d_out, int out_size, void* d_ws, size_t ws_size,
                              hipStream_t stream) {
    const float* x    = (const float*)d_in[0];  // [49152][1024] fp32
    const float* fc1w = (const float*)d_in[1];  // [4096][1024]  fp32
    const float* fc2w = (const float*)d_in[2];  // [1024][4096]  fp32
    const float* fc2b = (const float*)d_in[3];  // [1024]        fp32
    const float* mask = (const float*)d_in[4];  // [1024][1024]  fp32, s-major

    char* ws = (char*)d_ws;
    ushort* fc1T  = (ushort*)ws;                  //  8 MiB [1024 s][4096 d] bf16
    ushort* fc2wb = (ushort*)(ws + (8u  << 20));  //  8 MiB [1024 t][4096 d] bf16
    ushort* attnT = (ushort*)(ws + (16u << 20));  //  2 MiB [1024 t][1024 s] bf16
    ushort* xb    = (ushort*)(ws + (18u << 20));  // 96 MiB [49152][1024] bf16 (optional)
    const size_t XB_BYTES = 50331648ull * 2;
    const bool has_xb = ws_size >= (size_t)(18u << 20) + XB_BYTES;

    // weight prep (small)
    k_transpose<<<dim3(16, 64), 256, 0, stream>>>(fc1w, fc1T);
    k_cvt<<<2048, 256, 0, stream>>>(fc2w, fc2wb, 524288);
    // attn: attnT[t][s] = bf16((fc1T·fc2wb^T + bias) * mask)
    k_gemm<0, 0><<<dim3(8, 8), 256, 0, stream>>>(fc1T, fc2wb, fc2b, mask, attnT,
                                                 4096, 4096, 128);
    // main: out[n][t] = gelu(x·attnT^T), fp32 store
    if (has_xb) {
        k_cvt<<<24576, 256, 0, stream>>>(x, xb, 6291456);
        k_gemm<0, 1><<<dim3(8, 384), 256, 0, stream>>>(xb, attnT, nullptr, nullptr,
                                                       d_out, 1024, 1024, 32);
    } else {
        k_gemm<1, 1><<<dim3(8, 384), 256, 0, stream>>>(x, attnT, nullptr, nullptr,
                                                       d_out, 1024, 1024, 32);
    }
}